// Round 5
// baseline (265.228 us; speedup 1.0000x reference)
//
#include <hip/hip_runtime.h>
#include <hip/hip_cooperative_groups.h>
#include <hip/hip_fp16.h>
#include <math.h>

namespace cg = cooperative_groups;

// Problem constants (fixed by setup_inputs): B=2, K=128, L=4096, DK=DL=128, HID=128
constexpr int BB = 2;
constexpr int KK = 128;
constexpr int LL = 4096;
constexpr int DD = 128;   // DK == DL
constexpr int HH = 128;   // HID

__device__ __forceinline__ float4 ld4(const float* p) {
    return *reinterpret_cast<const float4*>(p);
}

// packed fp16 max (ROCm headers lack a usable __hmax2) — emits v_pk_max_f16
__device__ __forceinline__ __half2 hmax2(__half2 a, __half2 b) {
    unsigned ua = __builtin_bit_cast(unsigned, a);
    unsigned ub = __builtin_bit_cast(unsigned, b);
    unsigned ud;
    asm("v_pk_max_f16 %0, %1, %2" : "=v"(ud) : "v"(ua), "v"(ub));
    return __builtin_bit_cast(__half2, ud);
}

// duplicate fp16(x) into both halves of a dword (for SGPR-broadcast pk operands)
__device__ __forceinline__ uint32_t duph(float x) {
    __half h = __float2half(x);
    unsigned short us = __builtin_bit_cast(unsigned short, h);
    return (uint32_t)us * 0x10001u;
}

// ---------------------------------------------------------------------------
// One cooperative kernel, 512 blocks x 256 threads, 3 phases w/ grid.sync().
// Phase 1 (blocks 0..263): GEMM -> u_dup (fp16-dup), vT (fp16 transposed), w2_dup
// Phase 2 (all 512):       scores -> d_out (f32), half2 packs two adjacent l
// Phase 3 (blocks 0..255): in-place row softmax of d_out
// ---------------------------------------------------------------------------
__global__ __launch_bounds__(256) void fused_all(
    const float* __restrict__ inA, const float* __restrict__ inB,
    const float* __restrict__ W1, const float* __restrict__ b1,
    const float* __restrict__ w2,
    uint32_t* __restrict__ u_dup, uint32_t* __restrict__ w2_dup,
    __half* __restrict__ vT, float* __restrict__ out)
{
    cg::grid_group grid = cg::this_grid();

    __shared__ __align__(16) float sIn[32 * 128];   // 16 KiB (phase 1)
    __shared__ float sT[128 * 33];                  // 16.9 KiB (phase 1, reused ph3)

    const int tid = threadIdx.x;

    // ============================ Phase 1 ==================================
    if (blockIdx.x < 264) {
        const int row0 = blockIdx.x * 32;
        const bool isA = (row0 < BB * KK);
        const float* src = isA ? (inA + (size_t)row0 * DD)
                               : (inB + (size_t)(row0 - BB * KK) * DD);
        const float* w   = W1 + (isA ? 0 : DD * HH);

        #pragma unroll
        for (int j = 0; j < 4; ++j) {
            const int idx = tid + 256 * j;
            reinterpret_cast<float4*>(sIn)[idx] =
                reinterpret_cast<const float4*>(src)[idx];
        }
        __syncthreads();

        const int tx = tid & 31;   // cols tx*4 .. tx*4+3  (h)
        const int ty = tid >> 5;   // rows ty*4 .. ty*4+3

        float accx[4], accy[4], accz[4], accw[4];
        #pragma unroll
        for (int r = 0; r < 4; ++r) { accx[r] = accy[r] = accz[r] = accw[r] = 0.f; }

        for (int d0 = 0; d0 < DD; d0 += 4) {
            float4 w4[4];
            #pragma unroll
            for (int dd = 0; dd < 4; ++dd)
                w4[dd] = ld4(&w[(size_t)(d0 + dd) * HH + tx * 4]);
            float a[4][4];
            #pragma unroll
            for (int r = 0; r < 4; ++r) {
                float4 a4 = ld4(&sIn[(ty * 4 + r) * 128 + d0]);
                a[r][0] = a4.x; a[r][1] = a4.y; a[r][2] = a4.z; a[r][3] = a4.w;
            }
            #pragma unroll
            for (int dd = 0; dd < 4; ++dd) {
                const float4 wv = w4[dd];
                #pragma unroll
                for (int r = 0; r < 4; ++r) {
                    const float av = a[r][dd];
                    accx[r] = fmaf(av, wv.x, accx[r]);
                    accy[r] = fmaf(av, wv.y, accy[r]);
                    accz[r] = fmaf(av, wv.z, accz[r]);
                    accw[r] = fmaf(av, wv.w, accw[r]);
                }
            }
        }

        if (isA) {
            const float4 bb = ld4(&b1[tx * 4]);
            #pragma unroll
            for (int r = 0; r < 4; ++r) {
                uint4 o;
                o.x = duph(accx[r] + bb.x);
                o.y = duph(accy[r] + bb.y);
                o.z = duph(accz[r] + bb.z);
                o.w = duph(accw[r] + bb.w);
                *reinterpret_cast<uint4*>(
                    &u_dup[(size_t)(row0 + ty * 4 + r) * HH + tx * 4]) = o;
            }
            if (blockIdx.x == 0 && tid < HH) w2_dup[tid] = duph(w2[tid]);
        } else {
            #pragma unroll
            for (int r = 0; r < 4; ++r) {
                const int l = ty * 4 + r;
                sT[(tx * 4 + 0) * 33 + l] = accx[r];
                sT[(tx * 4 + 1) * 33 + l] = accy[r];
                sT[(tx * 4 + 2) * 33 + l] = accz[r];
                sT[(tx * 4 + 3) * 33 + l] = accw[r];
            }
            __syncthreads();
            const int h    = tid >> 1;
            const int half = tid & 1;
            const int rowB = row0 - BB * KK;
            const int bsel = rowB >> 12;
            const int l0   = (rowB & 4095) + half * 16;
            uint32_t o[8];
            #pragma unroll
            for (int i = 0; i < 8; ++i) {
                const float lo = sT[h * 33 + half * 16 + 2 * i];
                const float hi = sT[h * 33 + half * 16 + 2 * i + 1];
                o[i] = __builtin_bit_cast(uint32_t, __floats2half2_rn(lo, hi));
            }
            uint32_t* dst = reinterpret_cast<uint32_t*>(vT) +
                            ((size_t)(bsel * HH + h) * LL + l0) / 2;
            uint4 s0; s0.x = o[0]; s0.y = o[1]; s0.z = o[2]; s0.w = o[3];
            uint4 s1; s1.x = o[4]; s1.y = o[5]; s1.z = o[6]; s1.w = o[7];
            *reinterpret_cast<uint4*>(dst)     = s0;
            *reinterpret_cast<uint4*>(dst + 4) = s1;
        }
    }

    __threadfence();
    grid.sync();

    // ============================ Phase 2 ==================================
    {
        int bi = blockIdx.x;
        const int kt = bi & 31;  bi >>= 5;
        const int lt = bi & 7;   bi >>= 3;
        const int b  = bi;

        const int lp = lt * 256 + tid;   // l-pair index; l = 2*lp
        const uint32_t* vp = reinterpret_cast<const uint32_t*>(vT)
                             + (size_t)b * HH * (LL / 2) + lp;
        const uint32_t* up = u_dup + (size_t)(b * KK + kt * 4) * HH;

        float2 facc[4];
        #pragma unroll
        for (int k = 0; k < 4; ++k) { facc[k].x = 0.f; facc[k].y = 0.f; }

        const __half2 hz = __float2half2_rn(0.f);

        for (int g = 0; g < 8; ++g) {       // 16 h per iter, f32 flush each iter
            __half2 acc[4];
            #pragma unroll
            for (int k = 0; k < 4; ++k) acc[k] = hz;

            #pragma unroll
            for (int c = 0; c < 2; ++c) {
                const int h0 = g * 16 + c * 8;
                uint32_t v[8];
                #pragma unroll
                for (int j = 0; j < 8; ++j)
                    v[j] = vp[(size_t)(h0 + j) * (LL / 2)];
                #pragma unroll
                for (int k = 0; k < 4; ++k) {
                    #pragma unroll
                    for (int j = 0; j < 8; ++j) {
                        const __half2 uu = __builtin_bit_cast(__half2, up[k * HH + h0 + j]);
                        const __half2 ww = __builtin_bit_cast(__half2, w2_dup[h0 + j]);
                        __half2 t = __hadd2(__builtin_bit_cast(__half2, v[j]), uu);
                        acc[k] = __hfma2(hmax2(t, hz), ww, acc[k]);
                    }
                }
            }
            #pragma unroll
            for (int k = 0; k < 4; ++k) {
                const float2 f = __half22float2(acc[k]);
                facc[k].x += f.x; facc[k].y += f.y;
            }
        }

        #pragma unroll
        for (int k = 0; k < 4; ++k)
            *reinterpret_cast<float2*>(
                &out[(size_t)(b * KK + kt * 4 + k) * LL + 2 * lp]) = facc[k];
    }

    __threadfence();
    grid.sync();

    // ============================ Phase 3 ==================================
    if (blockIdx.x < BB * KK) {
        float* redm = sT;       // reuse LDS
        float* reds = sT + 8;

        const int row = blockIdx.x;
        float* p = out + (size_t)row * LL;

        float4 x[4];
        #pragma unroll
        for (int j = 0; j < 4; ++j)
            x[j] = reinterpret_cast<const float4*>(p)[tid + 256 * j];

        float m = x[0].x;
        #pragma unroll
        for (int j = 0; j < 4; ++j)
            m = fmaxf(m, fmaxf(fmaxf(x[j].x, x[j].y), fmaxf(x[j].z, x[j].w)));
        #pragma unroll
        for (int off = 32; off > 0; off >>= 1)
            m = fmaxf(m, __shfl_xor(m, off, 64));

        const int lane = tid & 63, wv = tid >> 6;
        if (lane == 0) redm[wv] = m;
        __syncthreads();
        m = fmaxf(fmaxf(redm[0], redm[1]), fmaxf(redm[2], redm[3]));

        float s = 0.f;
        #pragma unroll
        for (int j = 0; j < 4; ++j) {
            x[j].x = expf(x[j].x - m); s += x[j].x;
            x[j].y = expf(x[j].y - m); s += x[j].y;
            x[j].z = expf(x[j].z - m); s += x[j].z;
            x[j].w = expf(x[j].w - m); s += x[j].w;
        }
        #pragma unroll
        for (int off = 32; off > 0; off >>= 1)
            s += __shfl_xor(s, off, 64);
        if (lane == 0) reds[wv] = s;
        __syncthreads();
        s = (reds[0] + reds[1]) + (reds[2] + reds[3]);

        const float inv = 1.0f / s;
        #pragma unroll
        for (int j = 0; j < 4; ++j) {
            x[j].x *= inv; x[j].y *= inv; x[j].z *= inv; x[j].w *= inv;
            reinterpret_cast<float4*>(p)[tid + 256 * j] = x[j];
        }
    }
}

// ---------------------------------------------------------------------------
extern "C" void kernel_launch(void* const* d_in, const int* in_sizes, int n_in,
                              void* d_out, int out_size, void* d_ws, size_t ws_size,
                              hipStream_t stream)
{
    const float* inA = (const float*)d_in[0];
    const float* inB = (const float*)d_in[1];
    const float* W1  = (const float*)d_in[2];
    const float* b1  = (const float*)d_in[3];
    const float* w2  = (const float*)d_in[4];
    float* out = (float*)d_out;

    uint32_t* u_dup  = (uint32_t*)d_ws;                            // 128 KiB
    uint32_t* w2_dup = (uint32_t*)((char*)d_ws + 128 * 1024);      // 512 B
    __half*   vT     = (__half*)((char*)d_ws + 128 * 1024 + 512);  // 2 MiB

    void* args[] = { (void*)&inA, (void*)&inB, (void*)&W1, (void*)&b1,
                     (void*)&w2, (void*)&u_dup, (void*)&w2_dup,
                     (void*)&vT, (void*)&out };
    hipLaunchCooperativeKernel((const void*)fused_all, dim3(512), dim3(256),
                               args, 0, stream);
}

// Round 6
// 32.778 us; speedup vs baseline: 8.0918x; 8.0918x over previous
//
#include <hip/hip_runtime.h>
#include <hip/hip_fp16.h>
#include <math.h>

// Problem constants (fixed by setup_inputs): B=2, K=128, L=4096, DK=DL=128, HID=128
constexpr int BB = 2;
constexpr int KK = 128;
constexpr int LL = 4096;
constexpr int DD = 128;   // DK == DL
constexpr int HH = 128;   // HID

__device__ __forceinline__ float4 ld4(const float* p) {
    return *reinterpret_cast<const float4*>(p);
}

// packed fp16 max (ROCm headers lack a usable __hmax2) — emits v_pk_max_f16
__device__ __forceinline__ __half2 hmax2(__half2 a, __half2 b) {
    unsigned ua = __builtin_bit_cast(unsigned, a);
    unsigned ub = __builtin_bit_cast(unsigned, b);
    unsigned ud;
    asm("v_pk_max_f16 %0, %1, %2" : "=v"(ud) : "v"(ua), "v"(ub));
    return __builtin_bit_cast(__half2, ud);
}

// duplicate fp16(x) into both halves of a dword (broadcast operand for pk ops)
__device__ __forceinline__ uint32_t duph(float x) {
    __half h = __float2half(x);
    unsigned short us = __builtin_bit_cast(unsigned short, h);
    return (uint32_t)us * 0x10001u;
}

// ---------------------------------------------------------------------------
// K1: A-rows -> u_dup[b*K+k][h] (fp16 dup'd in both dword halves)
//     B-rows -> vT[b][h][l]     (fp16, transposed: k2 packs two adjacent l)
//     block 0 also packs w2 -> w2_dup[h].
// fp32 math. 32 rows/block, 256 threads, 4x4 micro-tile. B-part transposes
// through a +1-padded f32 LDS tile.
// ---------------------------------------------------------------------------
__global__ __launch_bounds__(256) void k1_gemm(
    const float* __restrict__ inA, const float* __restrict__ inB,
    const float* __restrict__ W1, const float* __restrict__ b1,
    const float* __restrict__ w2,
    uint32_t* __restrict__ u_dup, uint32_t* __restrict__ w2_dup,
    __half* __restrict__ vT)
{
    __shared__ __align__(16) float sIn[32 * 128];   // 16 KiB input tile
    __shared__ float sT[128 * 33];                  // 16.9 KiB transpose tile

    const int row0 = blockIdx.x * 32;
    const bool isA = (row0 < BB * KK);
    const float* src = isA ? (inA + (size_t)row0 * DD)
                           : (inB + (size_t)(row0 - BB * KK) * DD);
    const float* w   = W1 + (isA ? 0 : DD * HH);

    const int tid = threadIdx.x;

    #pragma unroll
    for (int j = 0; j < 4; ++j) {
        const int idx = tid + 256 * j;
        reinterpret_cast<float4*>(sIn)[idx] =
            reinterpret_cast<const float4*>(src)[idx];
    }
    __syncthreads();

    const int tx = tid & 31;   // cols tx*4 .. tx*4+3  (h)
    const int ty = tid >> 5;   // rows ty*4 .. ty*4+3

    float accx[4], accy[4], accz[4], accw[4];
    #pragma unroll
    for (int r = 0; r < 4; ++r) { accx[r] = accy[r] = accz[r] = accw[r] = 0.f; }

    for (int d0 = 0; d0 < DD; d0 += 4) {
        float4 w4[4];
        #pragma unroll
        for (int dd = 0; dd < 4; ++dd)
            w4[dd] = ld4(&w[(size_t)(d0 + dd) * HH + tx * 4]);
        float a[4][4];
        #pragma unroll
        for (int r = 0; r < 4; ++r) {
            float4 a4 = ld4(&sIn[(ty * 4 + r) * 128 + d0]);
            a[r][0] = a4.x; a[r][1] = a4.y; a[r][2] = a4.z; a[r][3] = a4.w;
        }
        #pragma unroll
        for (int dd = 0; dd < 4; ++dd) {
            const float4 wv = w4[dd];
            #pragma unroll
            for (int r = 0; r < 4; ++r) {
                const float av = a[r][dd];
                accx[r] = fmaf(av, wv.x, accx[r]);
                accy[r] = fmaf(av, wv.y, accy[r]);
                accz[r] = fmaf(av, wv.z, accz[r]);
                accw[r] = fmaf(av, wv.w, accw[r]);
            }
        }
    }

    if (isA) {
        const float4 bb = ld4(&b1[tx * 4]);
        #pragma unroll
        for (int r = 0; r < 4; ++r) {
            uint4 o;
            o.x = duph(accx[r] + bb.x);
            o.y = duph(accy[r] + bb.y);
            o.z = duph(accz[r] + bb.z);
            o.w = duph(accw[r] + bb.w);
            *reinterpret_cast<uint4*>(
                &u_dup[(size_t)(row0 + ty * 4 + r) * HH + tx * 4]) = o;
        }
        if (blockIdx.x == 0 && tid < HH) w2_dup[tid] = duph(w2[tid]);
    } else {
        #pragma unroll
        for (int r = 0; r < 4; ++r) {
            const int l = ty * 4 + r;
            sT[(tx * 4 + 0) * 33 + l] = accx[r];
            sT[(tx * 4 + 1) * 33 + l] = accy[r];
            sT[(tx * 4 + 2) * 33 + l] = accz[r];
            sT[(tx * 4 + 3) * 33 + l] = accw[r];
        }
        __syncthreads();
        const int h    = tid >> 1;
        const int half = tid & 1;
        const int rowB = row0 - BB * KK;
        const int bsel = rowB >> 12;
        const int l0   = (rowB & 4095) + half * 16;
        uint32_t o[8];
        #pragma unroll
        for (int i = 0; i < 8; ++i) {
            const float lo = sT[h * 33 + half * 16 + 2 * i];
            const float hi = sT[h * 33 + half * 16 + 2 * i + 1];
            o[i] = __builtin_bit_cast(uint32_t, __floats2half2_rn(lo, hi));
        }
        uint32_t* dst = reinterpret_cast<uint32_t*>(vT) +
                        ((size_t)(bsel * HH + h) * LL + l0) / 2;
        uint4 s0; s0.x = o[0]; s0.y = o[1]; s0.z = o[2]; s0.w = o[3];
        uint4 s1; s1.x = o[4]; s1.y = o[5]; s1.z = o[6]; s1.w = o[7];
        *reinterpret_cast<uint4*>(dst)     = s0;
        *reinterpret_cast<uint4*>(dst + 4) = s1;
    }
}

// ---------------------------------------------------------------------------
// K2: fused score + softmax. One block per (b,k) row. 1024 threads (16 waves).
// Thread owns 2 l-pairs (4 l). scores stay in registers for the softmax.
// v-loads: 4 B/lane coalesced dwords from vT; u_dup/w2_dup via LDS broadcast.
// fp16 acc flushed to f32 every 16 h (same chain length as R4).
// ---------------------------------------------------------------------------
__global__ __launch_bounds__(1024) void k2_fused(
    const uint32_t* __restrict__ u_dup, const uint32_t* __restrict__ w2_dup,
    const __half* __restrict__ vT, float* __restrict__ out)
{
    __shared__ __align__(16) uint32_t sU[HH];   // 512 B (dup'd u row)
    __shared__ __align__(16) uint32_t sW[HH];   // 512 B (dup'd w2)
    __shared__ float redm[16];
    __shared__ float reds[16];

    const int row = blockIdx.x;           // = b*KK + k
    const int b   = row >> 7;
    const int tid = threadIdx.x;

    if (tid < HH) sU[tid] = u_dup[(size_t)row * HH + tid];
    else if (tid < 2 * HH) sW[tid - HH] = w2_dup[tid - HH];
    __syncthreads();

    const uint32_t* vpb = reinterpret_cast<const uint32_t*>(vT)
                          + (size_t)b * HH * (LL / 2);

    const __half2 hz = __float2half2_rn(0.f);

    // two l-pairs per thread: lp, lp + 1024
    float2 facc[2];
    facc[0].x = 0.f; facc[0].y = 0.f;
    facc[1].x = 0.f; facc[1].y = 0.f;

    for (int g = 0; g < 8; ++g) {          // 16 h per group
        const int h0 = g * 16;
        uint4 uc[4], wc[4];
        #pragma unroll
        for (int q = 0; q < 4; ++q) {
            uc[q] = *reinterpret_cast<const uint4*>(&sU[h0 + q * 4]);
            wc[q] = *reinterpret_cast<const uint4*>(&sW[h0 + q * 4]);
        }
        #pragma unroll
        for (int p = 0; p < 2; ++p) {
            const int lp = tid + p * 1024;
            uint32_t v[16];
            #pragma unroll
            for (int j = 0; j < 16; ++j)
                v[j] = vpb[(size_t)(h0 + j) * (LL / 2) + lp];

            __half2 acc = hz;
            #pragma unroll
            for (int q = 0; q < 4; ++q) {
                const uint32_t* uq = reinterpret_cast<const uint32_t*>(&uc[q]);
                const uint32_t* wq = reinterpret_cast<const uint32_t*>(&wc[q]);
                #pragma unroll
                for (int j = 0; j < 4; ++j) {
                    const __half2 uu = __builtin_bit_cast(__half2, uq[j]);
                    const __half2 ww = __builtin_bit_cast(__half2, wq[j]);
                    const __half2 vv = __builtin_bit_cast(__half2, v[q * 4 + j]);
                    __half2 t = __hadd2(vv, uu);
                    acc = __hfma2(hmax2(t, hz), ww, acc);
                }
            }
            const float2 f = __half22float2(acc);
            facc[p].x += f.x; facc[p].y += f.y;
        }
    }

    // ---------------- softmax over the row (4 scores/thread) ----------------
    float m = fmaxf(fmaxf(facc[0].x, facc[0].y), fmaxf(facc[1].x, facc[1].y));
    #pragma unroll
    for (int off = 32; off > 0; off >>= 1)
        m = fmaxf(m, __shfl_xor(m, off, 64));
    const int lane = tid & 63, wv = tid >> 6;
    if (lane == 0) redm[wv] = m;
    __syncthreads();
    if (tid < 16) {
        float mm = redm[tid];
        #pragma unroll
        for (int off = 8; off > 0; off >>= 1)
            mm = fmaxf(mm, __shfl_xor(mm, off, 64));
        redm[tid] = mm;
    }
    __syncthreads();
    m = redm[0];

    facc[0].x = expf(facc[0].x - m);
    facc[0].y = expf(facc[0].y - m);
    facc[1].x = expf(facc[1].x - m);
    facc[1].y = expf(facc[1].y - m);
    float s = (facc[0].x + facc[0].y) + (facc[1].x + facc[1].y);
    #pragma unroll
    for (int off = 32; off > 0; off >>= 1)
        s += __shfl_xor(s, off, 64);
    if (lane == 0) reds[wv] = s;
    __syncthreads();
    if (tid < 16) {
        float ss = reds[tid];
        #pragma unroll
        for (int off = 8; off > 0; off >>= 1)
            ss += __shfl_xor(ss, off, 64);
        reds[tid] = ss;
    }
    __syncthreads();
    s = reds[0];

    const float inv = 1.0f / s;
    float2 o0, o1;
    o0.x = facc[0].x * inv; o0.y = facc[0].y * inv;
    o1.x = facc[1].x * inv; o1.y = facc[1].y * inv;
    float* po = out + (size_t)row * LL;
    *reinterpret_cast<float2*>(&po[2 * tid])          = o0;
    *reinterpret_cast<float2*>(&po[2 * (tid + 1024)]) = o1;
}

// ---------------------------------------------------------------------------
extern "C" void kernel_launch(void* const* d_in, const int* in_sizes, int n_in,
                              void* d_out, int out_size, void* d_ws, size_t ws_size,
                              hipStream_t stream)
{
    const float* inA = (const float*)d_in[0];
    const float* inB = (const float*)d_in[1];
    const float* W1  = (const float*)d_in[2];
    const float* b1  = (const float*)d_in[3];
    const float* w2  = (const float*)d_in[4];
    float* out = (float*)d_out;

    uint32_t* u_dup  = (uint32_t*)d_ws;                            // 128 KiB
    uint32_t* w2_dup = (uint32_t*)((char*)d_ws + 128 * 1024);      // 512 B
    __half*   vT     = (__half*)((char*)d_ws + 128 * 1024 + 512);  // 2 MiB

    hipLaunchKernelGGL(k1_gemm, dim3(264), dim3(256), 0, stream,
                       inA, inB, W1, b1, w2, u_dup, w2_dup, vT);
    hipLaunchKernelGGL(k2_fused, dim3(BB * KK), dim3(1024), 0, stream,
                       u_dup, w2_dup, vT, out);
}